// Round 3
// baseline (761.453 us; speedup 1.0000x reference)
//
#include <hip/hip_runtime.h>

#define HID   15
#define TMAIN 1024
#define FUT   64
#define OUTW  (TMAIN + FUT)   // 1088

__device__ __forceinline__ float rcp_(float x)  { return __builtin_amdgcn_rcpf(x); }
__device__ __forceinline__ float exp2_(float x) { return __builtin_amdgcn_exp2f(x); }
__device__ __forceinline__ float sigm(float x)  { return rcp_(1.0f + exp2_(x * -1.442695040888963f)); }
__device__ __forceinline__ float tanh_(float x) {
    return __builtin_fmaf(2.0f, rcp_(1.0f + exp2_(x * -2.885390081777927f)), -1.0f);
}

// R3 mapping: 1 wave = 2 batch elements; lane = g*32 + r*16 + k.
//   g = batch in wave (0..1), r = gate-pair half (0: rows i,f; 1: rows g,o),
//   k = hidden unit (0..14; k==15 pad with zeroed weights -> h stays exactly 0).
// 4096 batches / 2 = 2048 waves = 2 waves/SIMD: the second wave fills the
// dependency/trans/LDS-latency gaps that capped R2 at 74% VALUBusy with
// 1 wave/SIMD. Per-lane work halves (2 rows instead of 4); per-lane registers
// drop from ~244 to ~190 (less AGPR copy traffic at the observed 132-arch-VGPR
// allocation). Gate exchange between the r-halves: one ds_swizzle (lane^16) per
// activated gate, latency hidden behind the L2-hh FMA block. Both halves then
// compute c/h redundantly with identical operations -> identical state.
// Activation select without divergence: act(x) = fma(A, rcp(1+exp2(B*x)), C),
// (A,B,C) per-lane constants (sigm or tanh).
// Output dot: 16-lane xor butterfly on own-unit h2*wlin (DS pipe; its result is
// only consumed by the os store / next future-step, slack is ample).
// h2 LDS read-back is issued at step end, unpacked at the NEXT step's L2-hh
// (first consumer) -> ~100 cycles of L1 work cover the round trip.
__global__ __launch_bounds__(256)
__attribute__((amdgpu_waves_per_eu(2, 2)))
void lstm_seq_kernel(const float* __restrict__ input,
                     const float* __restrict__ W_ih1, const float* __restrict__ W_hh1,
                     const float* __restrict__ b_ih1, const float* __restrict__ b_hh1,
                     const float* __restrict__ W_ih2, const float* __restrict__ W_hh2,
                     const float* __restrict__ b_ih2, const float* __restrict__ b_hh2,
                     const float* __restrict__ W_lin, const float* __restrict__ b_lin,
                     float* __restrict__ out)
{
    __shared__ float xs [4][2][64];   // [wave][batch][t] staged input tile
    __shared__ float os [4][2][64];   // output tile
    __shared__ float h1s[4][2][16];   // h broadcast slots [wave][batch][unit]
    __shared__ float h2s[4][2][16];

    const int tid  = threadIdx.x;
    const int wq   = tid >> 6;
    const int lane = tid & 63;
    const int g    = lane >> 5;         // batch in wave
    const int r    = (lane >> 4) & 1;   // gate-pair half
    const int k    = lane & 15;         // hidden unit (15 = pad)
    const int b0   = (blockIdx.x * 4 + wq) * 2;

    const bool pad = (k >= HID);
    const float m  = pad ? 0.0f : 1.0f;
    const int  kk  = pad ? 0 : k;

    // gate rows handled by this lane: rowA = gate 2r, rowB = gate 2r+1
    const int rowA = (2 * r)     * HID + kk;
    const int rowB = (2 * r + 1) * HID + kk;

    float w1a[16], w1b[16], w2ia[16], w2ib[16], w2ha[16], w2hb[16];
    #pragma unroll
    for (int j = 0; j < HID; ++j) {
        w1a [j] = m * W_hh1[rowA * HID + j];
        w1b [j] = m * W_hh1[rowB * HID + j];
        w2ia[j] = m * W_ih2[rowA * HID + j];
        w2ib[j] = m * W_ih2[rowB * HID + j];
        w2ha[j] = m * W_hh2[rowA * HID + j];
        w2hb[j] = m * W_hh2[rowB * HID + j];
    }
    w1a[15]=0.f; w1b[15]=0.f; w2ia[15]=0.f; w2ib[15]=0.f; w2ha[15]=0.f; w2hb[15]=0.f;

    const float wihA = m * W_ih1[rowA];
    const float wihB = m * W_ih1[rowB];
    const float bA1  = m * (b_ih1[rowA] + b_hh1[rowA]);
    const float bB1  = m * (b_ih1[rowB] + b_hh1[rowB]);
    const float bA2  = m * (b_ih2[rowA] + b_hh2[rowA]);
    const float bB2  = m * (b_ih2[rowB] + b_hh2[rowB]);
    const float wl   = m * W_lin[kk];
    const float blin = b_lin[0];

    // act constants: pair-A gate is sigm (i) on r=0, tanh (g) on r=1; pair-B
    // gate (f / o) is always sigm.
    const float Aa = r ? 2.0f : 1.0f;
    const float Ba = r ? -2.885390081777927f : -1.442695040888963f;
    const float Ca = r ? -1.0f : 0.0f;
    const bool  isg = (r != 0);

    float h1x[16];
    #pragma unroll
    for (int i = 0; i < 16; ++i) h1x[i] = 0.0f;
    // h2 carried as pending float4 reads (unpacked at first use next step)
    float4 cr0 = {0,0,0,0}, cr1 = {0,0,0,0}, cr2 = {0,0,0,0}, cr3 = {0,0,0,0};
    float c1 = 0.0f, c2 = 0.0f, outv = 0.0f;

    auto step = [&](float x, int c) {
        // ---- phase 1: layer-1 pre-acts (uses h1x from prev step's refresh) ----
        float aA0 = __builtin_fmaf(wihA, x, bA1), aA1 = 0.0f;
        float aB0 = __builtin_fmaf(wihB, x, bB1), aB1 = 0.0f;
        #pragma unroll
        for (int j = 0; j < 8; ++j) {
            aA0 = __builtin_fmaf(w1a[j],   h1x[j],   aA0);
            aA1 = __builtin_fmaf(w1a[j+8], h1x[j+8], aA1);
            aB0 = __builtin_fmaf(w1b[j],   h1x[j],   aB0);
            aB1 = __builtin_fmaf(w1b[j+8], h1x[j+8], aB1);
        }
        const float pa = aA0 + aA1;
        const float pb = aB0 + aB1;

        // ---- phase 2: activations + gate exchange (DS pipe) ----
        const float va  = __builtin_fmaf(Aa, rcp_(1.0f + exp2_(pa * Ba)), Ca);
        const float vb  = sigm(pb);
        const float va2 = __shfl_xor(va, 16);
        const float vb2 = __shfl_xor(vb, 16);

        // ---- phase 3: layer-2 hh row A (uses prev h2; covers swizzle + the
        //      pending h2 LDS reads issued at the end of the previous step) ----
        float h2x[16];
        h2x[0]=cr0.x;  h2x[1]=cr0.y;  h2x[2]=cr0.z;  h2x[3]=cr0.w;
        h2x[4]=cr1.x;  h2x[5]=cr1.y;  h2x[6]=cr1.z;  h2x[7]=cr1.w;
        h2x[8]=cr2.x;  h2x[9]=cr2.y;  h2x[10]=cr2.z; h2x[11]=cr2.w;
        h2x[12]=cr3.x; h2x[13]=cr3.y; h2x[14]=cr3.z; h2x[15]=cr3.w;
        float dA0 = bA2, dA1 = 0.0f;
        #pragma unroll
        for (int j = 0; j < 8; ++j) {
            dA0 = __builtin_fmaf(w2ha[j],   h2x[j],   dA0);
            dA1 = __builtin_fmaf(w2ha[j+8], h2x[j+8], dA1);
        }

        // ---- phase 4: combine gates -> c1, h1 ----
        const float gi = isg ? va2 : va;
        const float gg = isg ? va  : va2;
        const float gf = isg ? vb2 : vb;
        const float go = isg ? vb  : vb2;
        c1 = __builtin_fmaf(gf, c1, gi * gg);
        const float h1n = go * tanh_(c1);

        // ---- phase 5: share h1; cover the read with layer-2 hh row B ----
        h1s[wq][g][k] = h1n;
        const float4 q0 = *(const float4*)&h1s[wq][g][0];
        const float4 q1 = *(const float4*)&h1s[wq][g][4];
        const float4 q2 = *(const float4*)&h1s[wq][g][8];
        const float4 q3 = *(const float4*)&h1s[wq][g][12];
        float dB0 = bB2, dB1 = 0.0f;
        #pragma unroll
        for (int j = 0; j < 8; ++j) {
            dB0 = __builtin_fmaf(w2hb[j],   h2x[j],   dB0);
            dB1 = __builtin_fmaf(w2hb[j+8], h2x[j+8], dB1);
        }

        // ---- phase 6: refresh h1x, layer-2 ih rows ----
        h1x[0]=q0.x;  h1x[1]=q0.y;  h1x[2]=q0.z;  h1x[3]=q0.w;
        h1x[4]=q1.x;  h1x[5]=q1.y;  h1x[6]=q1.z;  h1x[7]=q1.w;
        h1x[8]=q2.x;  h1x[9]=q2.y;  h1x[10]=q2.z; h1x[11]=q2.w;
        h1x[12]=q3.x; h1x[13]=q3.y; h1x[14]=q3.z; h1x[15]=q3.w;
        #pragma unroll
        for (int j = 0; j < 8; ++j) {
            dA0 = __builtin_fmaf(w2ia[j],   h1x[j],   dA0);
            dA1 = __builtin_fmaf(w2ia[j+8], h1x[j+8], dA1);
            dB0 = __builtin_fmaf(w2ib[j],   h1x[j],   dB0);
            dB1 = __builtin_fmaf(w2ib[j+8], h1x[j+8], dB1);
        }
        const float pa2 = dA0 + dA1;
        const float pb2 = dB0 + dB1;

        // ---- phase 7: layer-2 activations + exchange ----
        const float ua  = __builtin_fmaf(Aa, rcp_(1.0f + exp2_(pa2 * Ba)), Ca);
        const float ub  = sigm(pb2);
        const float ua2 = __shfl_xor(ua, 16);
        const float ub2 = __shfl_xor(ub, 16);
        const float hi = isg ? ua2 : ua;
        const float hg = isg ? ua  : ua2;
        const float hf = isg ? ub2 : ub;
        const float ho = isg ? ub  : ub2;
        c2 = __builtin_fmaf(hf, c2, hi * hg);
        const float h2n = ho * tanh_(c2);

        // ---- phase 8: share h2 (reads consumed NEXT step); out butterfly ----
        h2s[wq][g][k] = h2n;
        cr0 = *(const float4*)&h2s[wq][g][0];
        cr1 = *(const float4*)&h2s[wq][g][4];
        cr2 = *(const float4*)&h2s[wq][g][8];
        cr3 = *(const float4*)&h2s[wq][g][12];
        float p = h2n * wl;                  // own-unit contribution
        p += __shfl_xor(p, 1);
        p += __shfl_xor(p, 2);
        p += __shfl_xor(p, 4);
        p += __shfl_xor(p, 8);
        const float ov = p + blin;
        os[wq][g][c] = ov;                   // 32 lanes same addr/value: OK
        outv = ov;
    };

    // ---- main T steps, tiles of 64 ----
    #pragma unroll 1
    for (int tile = 0; tile < TMAIN / 64; ++tile) {
        const int t0 = tile * 64;
        #pragma unroll
        for (int j = 0; j < 2; ++j)
            xs[wq][j][lane] = input[(size_t)(b0 + j) * TMAIN + t0 + lane];
        #pragma unroll 2
        for (int c = 0; c < 64; ++c)
            step(xs[wq][g][c], c);
        #pragma unroll
        for (int j = 0; j < 2; ++j)
            out[(size_t)(b0 + j) * OUTW + t0 + lane] = os[wq][j][lane];
    }

    // ---- autoregressive future steps ----
    #pragma unroll 1
    for (int c = 0; c < FUT; ++c)
        step(outv, c);
    #pragma unroll
    for (int j = 0; j < 2; ++j)
        out[(size_t)(b0 + j) * OUTW + TMAIN + lane] = os[wq][j][lane];
}

extern "C" void kernel_launch(void* const* d_in, const int* in_sizes, int n_in,
                              void* d_out, int out_size, void* d_ws, size_t ws_size,
                              hipStream_t stream)
{
    const float* input = (const float*)d_in[0];
    const float* W_ih1 = (const float*)d_in[1];
    const float* W_hh1 = (const float*)d_in[2];
    const float* b_ih1 = (const float*)d_in[3];
    const float* b_hh1 = (const float*)d_in[4];
    const float* W_ih2 = (const float*)d_in[5];
    const float* W_hh2 = (const float*)d_in[6];
    const float* b_ih2 = (const float*)d_in[7];
    const float* b_hh2 = (const float*)d_in[8];
    const float* W_lin = (const float*)d_in[9];
    const float* b_lin = (const float*)d_in[10];
    // d_in[11] = future (=64), compiled in as FUT

    // 4096 batches / (2 per wave * 4 waves per block) = 512 blocks
    lstm_seq_kernel<<<512, 256, 0, stream>>>(
        input, W_ih1, W_hh1, b_ih1, b_hh1,
        W_ih2, W_hh2, b_ih2, b_hh2, W_lin, b_lin,
        (float*)d_out);
}

// Round 4
// 672.634 us; speedup vs baseline: 1.1320x; 1.1320x over previous
//
#include <hip/hip_runtime.h>

#define HID   15
#define TMAIN 1024
#define FUT   64
#define OUTW  (TMAIN + FUT)   // 1088

__device__ __forceinline__ float rcp_(float x)  { return __builtin_amdgcn_rcpf(x); }
__device__ __forceinline__ float exp2_(float x) { return __builtin_amdgcn_exp2f(x); }
__device__ __forceinline__ float tanh_(float x) {
    return __builtin_fmaf(2.0f, rcp_(1.0f + exp2_(x * -2.885390081777927f)), -1.0f);
}

// compile-time unroller (j must be a constant for the DPP ctrl template arg)
template<int I> struct ic { static constexpr int v = I; };
template<int J, int N, class F>
__device__ __forceinline__ void unroll_for(F&& f) {
    if constexpr (J < N) { f(ic<J>{}); unroll_for<J + 1, N>(f); }
}

// DPP move: CTRL = 0x150+j -> row_newbcast:j (bcast lane j of each 16-lane row,
// gfx90a+/CDNA); 0x110+n -> row_shr:n. VALU pipe: replaces the LDS round trips
// (R2: 2x ~120 cyc/step) and the ds_swizzle butterfly.
template<int CTRL>
__device__ __forceinline__ float dppf(float x) {
    return __int_as_float(__builtin_amdgcn_update_dpp(
        0, __float_as_int(x), CTRL, 0xF, 0xF, true));
}

// sum over each 16-lane row, result broadcast to all lanes of the row
__device__ __forceinline__ float row_sum_bcast(float p) {
    p += dppf<0x111>(p);   // row_shr:1
    p += dppf<0x112>(p);   // row_shr:2
    p += dppf<0x114>(p);   // row_shr:4
    p += dppf<0x118>(p);   // row_shr:8  -> lane15 of each row has the full sum
    return dppf<0x15F>(p); // row_newbcast:15
}

// R4 mapping (= R1): 1 wave = 4 batches; lane = g*16 + k. g = batch (= DPP row!),
// k = hidden unit (15 = pad; zeroed weights keep its h/c exactly 0 through the
// recurrence: a=0 -> g-gate tanh(0)=0 -> c=0 -> h=0). Each lane computes all 4
// gates of its unit in-lane. All h distribution is DPP row_newbcast (no LDS in
// the recurrence at all); output dot is a DPP row reduction.
// Activation input scales (-log2e for sigm, -2log2e for tanh) are folded into
// the weights/biases at load: act = rcp(1+exp2(a)) / fma(2, rcp(1+exp2(a)), -1).
__global__ __launch_bounds__(256)
__attribute__((amdgpu_waves_per_eu(1, 1)))
void lstm_seq_kernel(const float* __restrict__ input,
                     const float* __restrict__ W_ih1, const float* __restrict__ W_hh1,
                     const float* __restrict__ b_ih1, const float* __restrict__ b_hh1,
                     const float* __restrict__ W_ih2, const float* __restrict__ W_hh2,
                     const float* __restrict__ b_ih2, const float* __restrict__ b_hh2,
                     const float* __restrict__ W_lin, const float* __restrict__ b_lin,
                     float* __restrict__ out)
{
    __shared__ float xs[4][4][64];   // [wave][batch][t] staged input tile
    __shared__ float os[4][4][64];   // output tile

    const int tid  = threadIdx.x;
    const int wq   = tid >> 6;
    const int lane = tid & 63;
    const int g    = lane >> 4;       // batch subgroup == DPP row
    const int k    = lane & 15;       // hidden unit (15 = pad)
    const int b0   = (blockIdx.x * 4 + wq) * 4;

    const bool pad = (k >= HID);
    const float m  = pad ? 0.0f : 1.0f;
    const int  kk  = pad ? 0 : k;

    // act-input scale per gate (i,f,g,o): sigm rows get -log2e, tanh row -2log2e
    const float L2E = 1.442695040888963f;
    const float sA[4] = {-L2E, -L2E, -2.0f * L2E, -L2E};

    float w1[4][HID], w2i[4][HID], w2h[4][HID];
    float wih1[4], bb1[4], bb2[4];
    #pragma unroll
    for (int gi = 0; gi < 4; ++gi) {
        const int row = gi * HID + kk;
        const float s = m * sA[gi];
        wih1[gi] = s * W_ih1[row];
        bb1[gi]  = s * (b_ih1[row] + b_hh1[row]);
        bb2[gi]  = s * (b_ih2[row] + b_hh2[row]);
        #pragma unroll
        for (int c = 0; c < HID; ++c) {
            w1 [gi][c] = s * W_hh1[row * HID + c];
            w2i[gi][c] = s * W_ih2[row * HID + c];
            w2h[gi][c] = s * W_hh2[row * HID + c];
        }
    }
    const float wl   = m * W_lin[kk];
    const float blin = b_lin[0];

    float h1p = 0.0f, h2p = 0.0f;     // own unit's h (distribution is via DPP)
    float c1 = 0.0f, c2 = 0.0f, outv = 0.0f;

    auto step = [&](float x, int c) {
        // ---- layer-1 pre-acts: a_gi = s*(W_ih1 x + W_hh1 h1 + b) ----
        float a0 = __builtin_fmaf(wih1[0], x, bb1[0]);
        float a1 = __builtin_fmaf(wih1[1], x, bb1[1]);
        float a2 = __builtin_fmaf(wih1[2], x, bb1[2]);
        float a3 = __builtin_fmaf(wih1[3], x, bb1[3]);
        unroll_for<0, HID>([&](auto jc) {
            constexpr int j = decltype(jc)::v;
            const float hb = dppf<0x150 + j>(h1p);   // h1[j] to whole row
            a0 = __builtin_fmaf(w1[0][j], hb, a0);
            a1 = __builtin_fmaf(w1[1][j], hb, a1);
            a2 = __builtin_fmaf(w1[2][j], hb, a2);
            a3 = __builtin_fmaf(w1[3][j], hb, a3);
        });

        // ---- layer-2 hh part (depends only on h2p -> overlaps L1 act latency)
        float d0 = bb2[0], d1 = bb2[1], d2 = bb2[2], d3 = bb2[3];
        unroll_for<0, HID>([&](auto jc) {
            constexpr int j = decltype(jc)::v;
            const float hb = dppf<0x150 + j>(h2p);
            d0 = __builtin_fmaf(w2h[0][j], hb, d0);
            d1 = __builtin_fmaf(w2h[1][j], hb, d1);
            d2 = __builtin_fmaf(w2h[2][j], hb, d2);
            d3 = __builtin_fmaf(w2h[3][j], hb, d3);
        });

        // ---- layer-1 activations, c1, h1 ----
        const float ig = rcp_(1.0f + exp2_(a0));
        const float fg = rcp_(1.0f + exp2_(a1));
        const float gg = __builtin_fmaf(2.0f, rcp_(1.0f + exp2_(a2)), -1.0f);
        const float og = rcp_(1.0f + exp2_(a3));
        c1 = __builtin_fmaf(fg, c1, ig * gg);
        const float h1n = og * tanh_(c1);

        // ---- layer-2 ih part (new h1) ----
        unroll_for<0, HID>([&](auto jc) {
            constexpr int j = decltype(jc)::v;
            const float hb = dppf<0x150 + j>(h1n);
            d0 = __builtin_fmaf(w2i[0][j], hb, d0);
            d1 = __builtin_fmaf(w2i[1][j], hb, d1);
            d2 = __builtin_fmaf(w2i[2][j], hb, d2);
            d3 = __builtin_fmaf(w2i[3][j], hb, d3);
        });

        // ---- layer-2 activations, c2, h2 ----
        const float i2 = rcp_(1.0f + exp2_(d0));
        const float f2 = rcp_(1.0f + exp2_(d1));
        const float g2 = __builtin_fmaf(2.0f, rcp_(1.0f + exp2_(d2)), -1.0f);
        const float o2 = rcp_(1.0f + exp2_(d3));
        c2 = __builtin_fmaf(f2, c2, i2 * g2);
        const float h2n = o2 * tanh_(c2);

        // ---- out = <W_lin, h2> + b via DPP row reduction ----
        const float ov = row_sum_bcast(wl * h2n) + blin;
        os[wq][g][c] = ov;            // 16 lanes same addr/value: OK

        h1p = h1n; h2p = h2n; outv = ov;
    };

    // ---- main T steps, tiles of 64 ----
    #pragma unroll 1
    for (int tile = 0; tile < TMAIN / 64; ++tile) {
        const int t0 = tile * 64;
        #pragma unroll
        for (int j = 0; j < 4; ++j)
            xs[wq][j][lane] = input[(size_t)(b0 + j) * TMAIN + t0 + lane];
        #pragma unroll 2
        for (int c = 0; c < 64; ++c)
            step(xs[wq][g][c], c);
        #pragma unroll
        for (int j = 0; j < 4; ++j)
            out[(size_t)(b0 + j) * OUTW + t0 + lane] = os[wq][j][lane];
    }

    // ---- autoregressive future steps: x = previous out (in-lane) ----
    #pragma unroll 1
    for (int c = 0; c < FUT; ++c)
        step(outv, c);
    #pragma unroll
    for (int j = 0; j < 4; ++j)
        out[(size_t)(b0 + j) * OUTW + TMAIN + lane] = os[wq][j][lane];
}

extern "C" void kernel_launch(void* const* d_in, const int* in_sizes, int n_in,
                              void* d_out, int out_size, void* d_ws, size_t ws_size,
                              hipStream_t stream)
{
    const float* input = (const float*)d_in[0];
    const float* W_ih1 = (const float*)d_in[1];
    const float* W_hh1 = (const float*)d_in[2];
    const float* b_ih1 = (const float*)d_in[3];
    const float* b_hh1 = (const float*)d_in[4];
    const float* W_ih2 = (const float*)d_in[5];
    const float* W_hh2 = (const float*)d_in[6];
    const float* b_ih2 = (const float*)d_in[7];
    const float* b_hh2 = (const float*)d_in[8];
    const float* W_lin = (const float*)d_in[9];
    const float* b_lin = (const float*)d_in[10];
    // d_in[11] = future (=64), compiled in as FUT

    // 4096 batches / (4 per wave * 4 waves per block) = 256 blocks
    lstm_seq_kernel<<<256, 256, 0, stream>>>(
        input, W_ih1, W_hh1, b_ih1, b_hh1,
        W_ih2, W_hh2, b_ih2, b_hh2, W_lin, b_lin,
        (float*)d_out);
}